// Round 3
// baseline (36.577 us; speedup 1.0000x reference)
//
#include <hip/hip_runtime.h>
#include <math.h>

// RDF with Gaussian smearing, N=512 points, 400 bins. SINGLE dispatch:
// 128 blocks histogram unordered pairs into LDS, store partials to ws,
// last-finished block reduces + normalizes + writes all outputs.
// out layout: count[0..399], bins[400..800] (401 vals), rdf[801..1200]
#define NBINS 400
#define NPTS  512
#define RMAXF 13.635f
#define BOXF  (2.0f * RMAXF)
#define NBLK  128

__global__ __launch_bounds__(256) void rdf_fused(const float* __restrict__ pos,
                                                 float* __restrict__ part,
                                                 unsigned* __restrict__ ctr,
                                                 float* __restrict__ out) {
    __shared__ float hist[NBINS];
    __shared__ float ssum[4];
    __shared__ unsigned amLast;
    const int tid = threadIdx.x;

    for (int b = tid; b < NBINS; b += 256) hist[b] = 0.0f;
    __syncthreads();

    const float width = RMAXF / 399.0f;            // offsets spacing
    const float inv_w = 399.0f / RMAXF;
    const float coeff = -0.5f * inv_w * inv_w;     // -0.5 / width^2
    const float CUT   = 6.5f;                      // +/-6.5 sigma window

    // Unordered pairs (histogram of ordered pairs = 2x this; the factor
    // cancels in count/total): slot p -> i = p>>8, k = (p&255)+1,
    // j = (i+k) mod 512. k==256 pairs appear for both endpoints; keep i<256.
    const int total = NPTS * 256;                  // 131072 slots
    for (int p = blockIdx.x * 256 + tid; p < total; p += NBLK * 256) {
        const int i = p >> 8;
        const int k = (p & 255) + 1;
        if (k == 256 && i >= 256) continue;
        const int j = (i + k) & (NPTS - 1);
        float dx = fabsf(pos[3*i+0] - pos[3*j+0]);
        float dy = fabsf(pos[3*i+1] - pos[3*j+1]);
        float dz = fabsf(pos[3*i+2] - pos[3*j+2]);
        if (dx > RMAXF) dx = BOXF - dx;             // minimum-image fold
        if (dy > RMAXF) dy = BOXF - dy;
        if (dz > RMAXF) dz = BOXF - dz;
        const float dist = sqrtf(dx*dx + dy*dy + dz*dz);
        if (dist <= 0.0f) continue;                 // matches reference self-mask
        const float c = dist * inv_w;               // distance in bin widths
        int b0 = (int)ceilf(c - CUT);
        int b1 = (int)floorf(c + CUT);
        if (b0 < 0) b0 = 0;
        if (b1 > NBINS - 1) b1 = NBINS - 1;
        for (int b = b0; b <= b1; ++b) {
            const float d = dist - (float)b * width;
            atomicAdd(&hist[b], __expf(coeff * d * d));
        }
    }
    __syncthreads();
    for (int b = tid; b < NBINS; b += 256)
        part[blockIdx.x * NBINS + b] = hist[b];

    // Release partials, bump completion counter; mod-128 test is robust to
    // any counter start value (0xAA poison, no reset needed; 2^32 % 128 == 0).
    __threadfence();
    __syncthreads();
    if (tid == 0) {
        const unsigned old = atomicAdd(ctr, 1u);
        amLast = ((old & (NBLK - 1)) == (NBLK - 1)) ? 1u : 0u;
    }
    __syncthreads();
    if (!amLast) return;

    __threadfence();   // acquire: see all blocks' partials
    float v0 = 0.0f, v1 = 0.0f;
    #pragma unroll 8
    for (int p = 0; p < NBLK; ++p) v0 += part[p * NBINS + tid];
    if (tid < NBINS - 256) {
        #pragma unroll 8
        for (int p = 0; p < NBLK; ++p) v1 += part[p * NBINS + tid + 256];
    }

    // total = sum over all bins
    float s = v0 + v1;
    #pragma unroll
    for (int o = 32; o > 0; o >>= 1) s += __shfl_down(s, o, 64);
    if ((tid & 63) == 0) ssum[tid >> 6] = s;
    __syncthreads();
    const float tot = ssum[0] + ssum[1] + ssum[2] + ssum[3];

    // count + rdf (rdf = count * V/vol_bin = count * 400^3/(3b^2+3b+1))
    const float C3 = 400.0f * 400.0f * 400.0f;
    const float cf0 = v0 / tot;
    out[tid] = cf0;
    out[801 + tid] = cf0 * C3 / (3.0f*tid*tid + 3.0f*tid + 1.0f);
    if (tid < NBINS - 256) {
        const int b = tid + 256;
        const float cf1 = v1 / tot;
        out[b] = cf1;
        out[801 + b] = cf1 * C3 / (3.0f*(float)b*b + 3.0f*b + 1.0f);
    }
    // bins = linspace(0, R_MAX, 401)
    out[400 + tid] = (float)tid * (RMAXF / 400.0f);
    if (tid + 256 <= 400)
        out[400 + tid + 256] = (float)(tid + 256) * (RMAXF / 400.0f);
}

extern "C" void kernel_launch(void* const* d_in, const int* in_sizes, int n_in,
                              void* d_out, int out_size, void* d_ws, size_t ws_size,
                              hipStream_t stream) {
    const float* pos = (const float*)d_in[0];
    float* out = (float*)d_out;
    float* part = (float*)d_ws;                         // NBLK*NBINS floats
    unsigned* ctr = (unsigned*)(part + NBLK * NBINS);   // completion counter

    rdf_fused<<<NBLK, 256, 0, stream>>>(pos, part, ctr, out);
}

// Round 4
// 20.939 us; speedup vs baseline: 1.7469x; 1.7469x over previous
//
#include <hip/hip_runtime.h>
#include <math.h>

// RDF with Gaussian smearing, N=512 points, 400 bins. Two dispatches:
// K1: 128 blocks histogram unordered pairs into LDS, plain-store partials.
// K2: 1 block reduces partials, normalizes, writes count/bins/rdf.
// out layout: count[0..399], bins[400..800] (401 vals), rdf[801..1200]
#define NBINS 400
#define NPTS  512
#define RMAXF 13.635f
#define BOXF  (2.0f * RMAXF)
#define NPART 128

__global__ __launch_bounds__(256) void rdf_hist(const float* __restrict__ pos,
                                                float* __restrict__ part) {
    __shared__ float hist[NBINS];
    for (int b = threadIdx.x; b < NBINS; b += 256) hist[b] = 0.0f;
    __syncthreads();

    const float width = RMAXF / 399.0f;            // offsets spacing
    const float inv_w = 399.0f / RMAXF;
    const float coeff = -0.5f * inv_w * inv_w;     // -0.5 / width^2
    const float CUT   = 5.5f;                      // +/-5.5 sigma (tail ~2.7e-7 rel)

    // Unordered pairs (ordered histogram = 2x this; factor cancels in
    // count/total): slot p -> i = p>>8, k = (p&255)+1, j = (i+k) mod 512.
    // k==256 pairs appear for both endpoints; keep only i<256.
    const int total = NPTS * 256;                  // 131072 slots
    for (int p = blockIdx.x * 256 + threadIdx.x; p < total; p += NPART * 256) {
        const int i = p >> 8;
        const int k = (p & 255) + 1;
        if (k == 256 && i >= 256) continue;
        const int j = (i + k) & (NPTS - 1);
        float dx = fabsf(pos[3*i+0] - pos[3*j+0]);
        float dy = fabsf(pos[3*i+1] - pos[3*j+1]);
        float dz = fabsf(pos[3*i+2] - pos[3*j+2]);
        if (dx > RMAXF) dx = BOXF - dx;             // minimum-image fold
        if (dy > RMAXF) dy = BOXF - dy;
        if (dz > RMAXF) dz = BOXF - dz;
        const float dist = sqrtf(dx*dx + dy*dy + dz*dz);
        if (dist <= 0.0f) continue;                 // matches reference self-mask
        const float c = dist * inv_w;               // distance in bin widths
        int b0 = (int)ceilf(c - CUT);
        int b1 = (int)floorf(c + CUT);
        if (b0 < 0) b0 = 0;
        if (b1 > NBINS - 1) b1 = NBINS - 1;
        for (int b = b0; b <= b1; ++b) {
            const float d = dist - (float)b * width;
            atomicAdd(&hist[b], __expf(coeff * d * d));
        }
    }
    __syncthreads();
    for (int b = threadIdx.x; b < NBINS; b += 256)
        part[blockIdx.x * NBINS + b] = hist[b];
}

__global__ __launch_bounds__(512) void rdf_final(const float* __restrict__ part,
                                                 float* __restrict__ out) {
    __shared__ float ssum[8];
    const int t = threadIdx.x;

    float v = 0.0f;
    if (t < NBINS) {
        #pragma unroll 16
        for (int p = 0; p < NPART; ++p) v += part[p * NBINS + t];
    }

    // total = sum over bins: wave(64) reduce then cross-wave via LDS
    float s = v;
    #pragma unroll
    for (int o = 32; o > 0; o >>= 1) s += __shfl_down(s, o, 64);
    if ((t & 63) == 0) ssum[t >> 6] = s;
    __syncthreads();
    if (t == 0) {
        float tot = 0.0f;
        #pragma unroll
        for (int w = 0; w < 8; ++w) tot += ssum[w];
        ssum[0] = tot;
    }
    __syncthreads();
    const float tot = ssum[0];

    if (t < NBINS) {
        const float cf = v / tot;
        out[t] = cf;                                   // count (normalized)
        // rdf = cf * V/vol_bin = cf * 400^3 / (3b^2+3b+1) (exact integer form)
        const float denom = (3.0f * t * t + 3.0f * t + 1.0f);
        out[801 + t] = cf * (400.0f * 400.0f * 400.0f) / denom;
    }
    if (t < NBINS + 1) {
        out[NBINS + t] = (float)t * (RMAXF / 400.0f);  // bins = linspace(0, R_MAX, 401)
    }
}

extern "C" void kernel_launch(void* const* d_in, const int* in_sizes, int n_in,
                              void* d_out, int out_size, void* d_ws, size_t ws_size,
                              hipStream_t stream) {
    const float* pos = (const float*)d_in[0];
    float* out = (float*)d_out;
    float* part = (float*)d_ws;   // NPART*NBINS floats, fully overwritten each call

    rdf_hist<<<NPART, 256, 0, stream>>>(pos, part);
    rdf_final<<<1, 512, 0, stream>>>(part, out);
}